// Round 14
// baseline (63.499 us; speedup 1.0000x reference)
//
#include <hip/hip_runtime.h>
#include <cmath>

// Local contrast normalization, fused tile kernel — occupancy variant.
// x: [64,512,512,1] f32. 9x9 Gaussian (separable, center 4.5), SAME zero pad.
// Tile: 64 wide x 16 tall, 256 threads. LDS = 16,128 B -> 8 blocks/CU
// (32 waves, 100% occupancy; r13 was 25.3 KB -> 6 blocks -> 57%).
// All phases TASK-LINEAR: addr linear in tid => every 16-consecutive-lane
// b128 group touches 16 consecutive float4s => conflict-free by construction.

struct W9 { float w[9]; };

typedef float nf4 __attribute__((ext_vector_type(4)));  // nontemporal store

#define HW   512
#define HW4  128   // f4 per image row
#define TSY  16    // output tile height
#define NH1  18    // h1/dd width in f4 (72 cols: ox-4 .. ox+67)
#define NH2  16    // h2/out width in f4 (64 cols)
#define RH1  32    // h1 rows  (oy-8 .. oy+23)
#define RDD  24    // dd/h2 rows (oy-4 .. oy+19)

__device__ __forceinline__ float4 conv9(const float* X, const float* w) {
    float4 o = {0.f, 0.f, 0.f, 0.f};
#pragma unroll
    for (int j = 0; j < 9; ++j) {
        o.x = fmaf(w[j], X[j + 0], o.x);
        o.y = fmaf(w[j], X[j + 1], o.y);
        o.z = fmaf(w[j], X[j + 2], o.z);
        o.w = fmaf(w[j], X[j + 3], o.w);
    }
    return o;
}

__global__ __launch_bounds__(256, 8) void lcn_kernel(const float* __restrict__ x,
                                                     float* __restrict__ out,
                                                     W9 wts) {
    __shared__ float4 sm[RH1 * NH1 + RDD * NH1];  // 576 + 432 f4 = 16,128 B
    float4* h1 = sm;                 // [32][18]
    float4* dd = sm + RH1 * NH1;     // [24][18]
    float4* h2 = sm;                 // [24][16] = 384 f4, aliases h1 (dead after p2)

    const int tid = threadIdx.x;
    const int oxf = blockIdx.x * NH2;        // f4 col of output tile
    const int oy  = blockIdx.y * TSY;
    const float* xb = x + (size_t)blockIdx.z * HW * HW;
    float* ob = out + (size_t)blockIdx.z * HW * HW;

    float w[9];
#pragma unroll
    for (int i = 0; i < 9; ++i) w[i] = wts.w[i];

    // ---- p1: h1[r][m] = h-conv(x) at row oy-8+r, f4 col oxf-1+m ----
    // 576 tasks = 2 full sweeps + 64-task tail (static trip counts).
#pragma unroll
    for (int s = 0; s < 2; ++s) {
        int o = tid + s * 256;
        int r = o / NH1, m = o % NH1;
        int gy = oy - 8 + r;
        float4 o4 = {0.f, 0.f, 0.f, 0.f};
        if (gy >= 0 && gy < HW) {
            const float4* row = reinterpret_cast<const float4*>(xb + (size_t)gy * HW);
            float X[12];
#pragma unroll
            for (int k = 0; k < 3; ++k) {
                int g4 = oxf - 2 + m + k;
                float4 v = (g4 >= 0 && g4 < HW4) ? row[g4] : float4{0.f, 0.f, 0.f, 0.f};
                X[4 * k + 0] = v.x; X[4 * k + 1] = v.y;
                X[4 * k + 2] = v.z; X[4 * k + 3] = v.w;
            }
            o4 = conv9(X, w);
        }
        h1[o] = o4;
    }
    if (tid < 64) {
        int o = tid + 512;
        int r = o / NH1, m = o % NH1;
        int gy = oy - 8 + r;
        float4 o4 = {0.f, 0.f, 0.f, 0.f};
        if (gy >= 0 && gy < HW) {
            const float4* row = reinterpret_cast<const float4*>(xb + (size_t)gy * HW);
            float X[12];
#pragma unroll
            for (int k = 0; k < 3; ++k) {
                int g4 = oxf - 2 + m + k;
                float4 v = (g4 >= 0 && g4 < HW4) ? row[g4] : float4{0.f, 0.f, 0.f, 0.f};
                X[4 * k + 0] = v.x; X[4 * k + 1] = v.y;
                X[4 * k + 2] = v.z; X[4 * k + 3] = v.w;
            }
            o4 = conv9(X, w);
        }
        h1[o] = o4;
    }
    __syncthreads();

    // ---- p2: mean = v-conv(h1); dd = x - mean (zero outside image) ----
    // 432 outputs, task-linear: tap j reads h1[t + j*18] (conflict-free).
    {
        int t = tid;                          // 0..255
        {
            int r = t / NH1, m = t % NH1;
            float4 mean = {0.f, 0.f, 0.f, 0.f};
#pragma unroll
            for (int j = 0; j < 9; ++j) {
                const float4 h = h1[t + j * NH1];
                mean.x = fmaf(w[j], h.x, mean.x);
                mean.y = fmaf(w[j], h.y, mean.y);
                mean.z = fmaf(w[j], h.z, mean.z);
                mean.w = fmaf(w[j], h.w, mean.w);
            }
            int gy = oy - 4 + r;
            int g4 = oxf - 1 + m;
            float4 d = {0.f, 0.f, 0.f, 0.f};
            if (gy >= 0 && gy < HW && g4 >= 0 && g4 < HW4) {
                float4 xv = reinterpret_cast<const float4*>(xb + (size_t)gy * HW)[g4];
                d.x = xv.x - mean.x; d.y = xv.y - mean.y;
                d.z = xv.z - mean.z; d.w = xv.w - mean.w;
            }
            dd[t] = d;
        }
        if (tid < 176) {
            int t2 = tid + 256;
            int r = t2 / NH1, m = t2 % NH1;
            float4 mean = {0.f, 0.f, 0.f, 0.f};
#pragma unroll
            for (int j = 0; j < 9; ++j) {
                const float4 h = h1[t2 + j * NH1];
                mean.x = fmaf(w[j], h.x, mean.x);
                mean.y = fmaf(w[j], h.y, mean.y);
                mean.z = fmaf(w[j], h.z, mean.z);
                mean.w = fmaf(w[j], h.w, mean.w);
            }
            int gy = oy - 4 + r;
            int g4 = oxf - 1 + m;
            float4 d = {0.f, 0.f, 0.f, 0.f};
            if (gy >= 0 && gy < HW && g4 >= 0 && g4 < HW4) {
                float4 xv = reinterpret_cast<const float4*>(xb + (size_t)gy * HW)[g4];
                d.x = xv.x - mean.x; d.y = xv.y - mean.y;
                d.z = xv.z - mean.z; d.w = xv.w - mean.w;
            }
            dd[t2] = d;
        }
    }
    __syncthreads();

    // ---- p3: h2[r][n] = h-conv(dd^2), 24 rows x 16 f4 (384 tasks) ----
    {
        {
            int o = tid;
            int r = o >> 4, n = o & 15;
            float4 a = dd[r * NH1 + n];
            float4 b = dd[r * NH1 + n + 1];
            float4 c = dd[r * NH1 + n + 2];
            float X[12] = {a.x * a.x, a.y * a.y, a.z * a.z, a.w * a.w,
                           b.x * b.x, b.y * b.y, b.z * b.z, b.w * b.w,
                           c.x * c.x, c.y * c.y, c.z * c.z, c.w * c.w};
            h2[o] = conv9(X, w);
        }
        if (tid < 128) {
            int o = tid + 256;
            int r = o >> 4, n = o & 15;
            float4 a = dd[r * NH1 + n];
            float4 b = dd[r * NH1 + n + 1];
            float4 c = dd[r * NH1 + n + 2];
            float X[12] = {a.x * a.x, a.y * a.y, a.z * a.z, a.w * a.w,
                           b.x * b.x, b.y * b.y, b.z * b.z, b.w * b.w,
                           c.x * c.x, c.y * c.y, c.z * c.z, c.w * c.w};
            h2[o] = conv9(X, w);
        }
    }
    __syncthreads();

    // ---- p4: n2 = v-conv(h2); out = keep ? dd/sqrt(n2) : dd ----
    // 256 outputs = exactly one sweep; tap j reads h2[tid + j*16] (linear).
    {
        int r = tid >> 4, n = tid & 15;
        float4 n2 = {0.f, 0.f, 0.f, 0.f};
#pragma unroll
        for (int j = 0; j < 9; ++j) {
            const float4 h = h2[tid + j * NH2];
            n2.x = fmaf(w[j], h.x, n2.x);
            n2.y = fmaf(w[j], h.y, n2.y);
            n2.z = fmaf(w[j], h.z, n2.z);
            n2.w = fmaf(w[j], h.w, n2.w);
        }
        float4 dv = dd[(r + 4) * NH1 + n + 1];
        nf4 o;  // keep <=> sqrt(n2) > 0.5 <=> n2 > 0.25
        { float nr = rsqrtf(n2.x); o.x = (n2.x > 0.25f) ? dv.x * nr : dv.x; }
        { float nr = rsqrtf(n2.y); o.y = (n2.y > 0.25f) ? dv.y * nr : dv.y; }
        { float nr = rsqrtf(n2.z); o.z = (n2.z > 0.25f) ? dv.z * nr : dv.z; }
        { float nr = rsqrtf(n2.w); o.w = (n2.w > 0.25f) ? dv.w * nr : dv.w; }
        __builtin_nontemporal_store(o,
            reinterpret_cast<nf4*>(ob + (size_t)(oy + r) * HW) + oxf + n);
    }
}

static W9 make_w() {
    // reference: sigmah = 9/6, exponent divides by 2*sigmah = 3.0;
    // taps centered at 4.5 (asymmetric); separable: w1 = g1 / sum(g1).
    double g[9], s = 0.0;
    for (int i = 0; i < 9; ++i) {
        double off = (double)i - 4.5;
        g[i] = exp(-(off * off) / 3.0);
        s += g[i];
    }
    W9 r;
    for (int i = 0; i < 9; ++i) r.w[i] = (float)(g[i] / s);
    return r;
}

extern "C" void kernel_launch(void* const* d_in, const int* in_sizes, int n_in,
                              void* d_out, int out_size, void* d_ws, size_t ws_size,
                              hipStream_t stream) {
    const float* x = (const float*)d_in[0];
    float* out = (float*)d_out;
    W9 w = make_w();
    dim3 grid(HW / 64, HW / TSY, 64);  // 8 x 32 x 64
    lcn_kernel<<<grid, dim3(256), 0, stream>>>(x, out, w);
}

// Round 15
// 54.581 us; speedup vs baseline: 1.1634x; 1.1634x over previous
//
#include <hip/hip_runtime.h>
#include <cmath>

// Local contrast normalization, fused tile kernel — edge-specialized.
// x: [64,512,512,1] f32. 9x9 Gaussian (separable, center 4.5), SAME zero pad.
// Tile: 64 wide x 32 tall, 256 threads, 25.3 KB LDS (6 blocks/CU).
// r15: template<GUARD> body; interior blocks (66%) run with ZERO bounds
// checks (ranges compile-time provably in-image), edge blocks keep guards.
// All LDS phases task-linear or group-consecutive (conflict-free b128).

struct W9 { float w[9]; };

typedef float nf4 __attribute__((ext_vector_type(4)));  // nontemporal store

#define HW   512
#define HW4  128   // f4 per image row
#define TSY  32    // output tile height
#define NH1  18    // h1/dd width in f4 (72 cols: ox-4 .. ox+67)
#define NH2  16    // h2/out width in f4 (64 cols)
#define RH1  48    // h1 rows  (oy-8 .. oy+39)
#define RDD  40    // dd/h2 rows (oy-4 .. oy+35)

__device__ __forceinline__ float4 conv9(const float* X, const float* w) {
    float4 o = {0.f, 0.f, 0.f, 0.f};
#pragma unroll
    for (int j = 0; j < 9; ++j) {
        o.x = fmaf(w[j], X[j + 0], o.x);
        o.y = fmaf(w[j], X[j + 1], o.y);
        o.z = fmaf(w[j], X[j + 2], o.z);
        o.w = fmaf(w[j], X[j + 3], o.w);
    }
    return o;
}

template <bool G>   // G = guarded (edge block)
__device__ __forceinline__ void run_tile(const float* __restrict__ xb,
                                         float* __restrict__ ob,
                                         int oxf, int oy, const float* w,
                                         float4* sm, int tid) {
    float4* h1 = sm;                 // [48][18]
    float4* dd = sm + RH1 * NH1;     // [40][18]
    float4* h2 = sm;                 // [40][16], aliases h1 (dead after p2)

    // ---- p1: h1[r][m] = h-conv(x) at row oy-8+r, f4 col oxf-1+m ----
    for (int o = tid; o < RH1 * NH1; o += 256) {
        int r = o / NH1, m = o % NH1;
        int gy = oy - 8 + r;
        float4 o4 = {0.f, 0.f, 0.f, 0.f};
        if (!G || (gy >= 0 && gy < HW)) {
            const float4* row = reinterpret_cast<const float4*>(xb + (size_t)gy * HW);
            float X[12];
#pragma unroll
            for (int k = 0; k < 3; ++k) {
                int g4 = oxf - 2 + m + k;
                float4 v;
                if (G) v = (g4 >= 0 && g4 < HW4) ? row[g4] : float4{0.f, 0.f, 0.f, 0.f};
                else   v = row[g4];           // interior: provably in-range
                X[4 * k + 0] = v.x; X[4 * k + 1] = v.y;
                X[4 * k + 2] = v.z; X[4 * k + 3] = v.w;
            }
            o4 = conv9(X, w);
        }
        h1[o] = o4;
    }
    __syncthreads();

    // ---- p2: mean = v-conv(h1); dd = x - mean ----
    // task-linear: tap j reads h1[t + j*18] (addr linear in tid).
    for (int t = tid; t < RDD * NH1; t += 256) {
        int r = t / NH1, m = t % NH1;
        float4 mean = {0.f, 0.f, 0.f, 0.f};
#pragma unroll
        for (int j = 0; j < 9; ++j) {
            const float4 h = h1[t + j * NH1];
            mean.x = fmaf(w[j], h.x, mean.x);
            mean.y = fmaf(w[j], h.y, mean.y);
            mean.z = fmaf(w[j], h.z, mean.z);
            mean.w = fmaf(w[j], h.w, mean.w);
        }
        int gy = oy - 4 + r;
        int g4 = oxf - 1 + m;
        float4 d = {0.f, 0.f, 0.f, 0.f};
        if (!G) {
            float4 xv = reinterpret_cast<const float4*>(xb + (size_t)gy * HW)[g4];
            d.x = xv.x - mean.x; d.y = xv.y - mean.y;
            d.z = xv.z - mean.z; d.w = xv.w - mean.w;
        } else if (gy >= 0 && gy < HW && g4 >= 0 && g4 < HW4) {
            float4 xv = reinterpret_cast<const float4*>(xb + (size_t)gy * HW)[g4];
            d.x = xv.x - mean.x; d.y = xv.y - mean.y;
            d.z = xv.z - mean.z; d.w = xv.w - mean.w;
        }
        dd[t] = d;
    }
    __syncthreads();

    // ---- p3: h2[r][n] = h-conv(dd^2), 40 rows x 16 f4 ----
    for (int o = tid; o < RDD * NH2; o += 256) {
        int r = o / NH2, n = o % NH2;
        float4 a = dd[r * NH1 + n];
        float4 b = dd[r * NH1 + n + 1];
        float4 c = dd[r * NH1 + n + 2];
        float X[12] = {a.x * a.x, a.y * a.y, a.z * a.z, a.w * a.w,
                       b.x * b.x, b.y * b.y, b.z * b.z, b.w * b.w,
                       c.x * c.x, c.y * c.y, c.z * c.z, c.w * c.w};
        h2[o] = conv9(X, w);   // o == r*16 + n, contiguous
    }
    __syncthreads();

    // ---- p4: n2 = v-conv(h2); out = keep ? dd/sqrt(n2) : dd ----
    // 256 threads: n = tid%16 (group-consecutive), 16 row-groups of 2.
    {
        int n = tid % NH2, rg = tid / NH2;
        int r0 = rg * 2;
        float4 ring[9];
#pragma unroll
        for (int i = 0; i < 9; ++i) ring[i] = h2[(r0 + i) * NH2 + n];
#pragma unroll
        for (int k = 0; k < 2; ++k) {
            if (k) ring[(k + 8) % 9] = h2[(r0 + 8 + k) * NH2 + n];
            float4 n2 = {0.f, 0.f, 0.f, 0.f};
#pragma unroll
            for (int j = 0; j < 9; ++j) {
                const float4 h = ring[(k + j) % 9];
                n2.x = fmaf(w[j], h.x, n2.x);
                n2.y = fmaf(w[j], h.y, n2.y);
                n2.z = fmaf(w[j], h.z, n2.z);
                n2.w = fmaf(w[j], h.w, n2.w);
            }
            float4 dv = dd[(r0 + k + 4) * NH1 + n + 1];
            nf4 o;  // keep <=> sqrt(n2) > 0.5 <=> n2 > 0.25
            { float nr = rsqrtf(n2.x); o.x = (n2.x > 0.25f) ? dv.x * nr : dv.x; }
            { float nr = rsqrtf(n2.y); o.y = (n2.y > 0.25f) ? dv.y * nr : dv.y; }
            { float nr = rsqrtf(n2.z); o.z = (n2.z > 0.25f) ? dv.z * nr : dv.z; }
            { float nr = rsqrtf(n2.w); o.w = (n2.w > 0.25f) ? dv.w * nr : dv.w; }
            __builtin_nontemporal_store(o,
                reinterpret_cast<nf4*>(ob + (size_t)(oy + r0 + k) * HW) + oxf + n);
        }
    }
}

__global__ __launch_bounds__(256, 6) void lcn_kernel(const float* __restrict__ x,
                                                     float* __restrict__ out,
                                                     W9 wts) {
    __shared__ float4 sm[RH1 * NH1 + RDD * NH1];  // 25,344 B

    const int tid = threadIdx.x;
    const int oxf = blockIdx.x * NH2;
    const int oy  = blockIdx.y * TSY;
    const float* xb = x + (size_t)blockIdx.z * HW * HW;
    float* ob = out + (size_t)blockIdx.z * HW * HW;

    float w[9];
#pragma unroll
    for (int i = 0; i < 9; ++i) w[i] = wts.w[i];

    // interior: p1 x-range [oxf-2, oxf+19], p2 [oxf-1, oxf+17] in f4
    // (bx 1..6 -> 14..115 < 128 OK); y-range [oy-8, oy+39] (by 1..14 OK).
    const bool interior = (blockIdx.x > 0 && blockIdx.x < gridDim.x - 1 &&
                           blockIdx.y > 0 && blockIdx.y < gridDim.y - 1);
    if (interior) run_tile<false>(xb, ob, oxf, oy, w, sm, tid);
    else          run_tile<true >(xb, ob, oxf, oy, w, sm, tid);
}

static W9 make_w() {
    // reference: sigmah = 9/6, exponent divides by 2*sigmah = 3.0;
    // taps centered at 4.5 (asymmetric); separable: w1 = g1 / sum(g1).
    double g[9], s = 0.0;
    for (int i = 0; i < 9; ++i) {
        double off = (double)i - 4.5;
        g[i] = exp(-(off * off) / 3.0);
        s += g[i];
    }
    W9 r;
    for (int i = 0; i < 9; ++i) r.w[i] = (float)(g[i] / s);
    return r;
}

extern "C" void kernel_launch(void* const* d_in, const int* in_sizes, int n_in,
                              void* d_out, int out_size, void* d_ws, size_t ws_size,
                              hipStream_t stream) {
    const float* x = (const float*)d_in[0];
    float* out = (float*)d_out;
    W9 w = make_w();
    dim3 grid(HW / 64, HW / TSY, 64);  // 8 x 16 x 64
    lcn_kernel<<<grid, dim3(256), 0, stream>>>(x, out, w);
}